// Round 5
// baseline (140.381 us; speedup 1.0000x reference)
//
#include <hip/hip_runtime.h>
#include <hip/hip_bf16.h>

// Problem constants
#define B_    64
#define C_    64
#define N_    22
#define T_    1024
#define O_    64
#define KTOT  1408      // C_*N_
#define KSTEPS 44       // KTOT/32

typedef __bf16 bf16x8 __attribute__((ext_vector_type(8)));
typedef float  f32x4  __attribute__((ext_vector_type(4)));

// ---------------------------------------------------------------------------
// prep_all: grid 256 = 64 o x 4 kq. Each block redundantly computes the 22x22
// graph operators + F1/F2 (cheap), then folds its k-range [kq*352,+352) of
// Mfrag in A-fragment-major bf16 layout:
//   Mfrag[((ks*4+fo)*64 + l)*8 + j] = M[o = fo*16 + (l&15),
//                                       k = ks*32 + (l>>4)*8 + j]
// ---------------------------------------------------------------------------
__global__ __launch_bounds__(256) void prep_all(
    const float* __restrict__ adjp,
    const float* __restrict__ chebw,   // [3][64][64]
    const float* __restrict__ chebb,   // [64]
    const float* __restrict__ aggw,    // [64][64][22]
    const float* __restrict__ aggb,    // [64]
    __bf16* __restrict__ Mfrag,        // [176*512]
    float* __restrict__ constv)        // [64]
{
    const int o   = blockIdx.x >> 2;
    const int kq  = blockIdx.x & 3;
    const int tid = threadIdx.x;
    __shared__ float sm[484];     // s = -D^-1/2 A D^-1/2   (C1)
    __shared__ float c2[484];     // adj (temp), then C2 = 2 s^2 - I
    __shared__ float dis[22];
    __shared__ float aggs[KTOT];  // aggw[o,:,:]
    __shared__ float F1[KTOT];
    __shared__ float F2[KTOT];
    __shared__ float red[256];

    for (int e = tid; e < 484; e += 256) {
        int i = e / 22, j = e - i * 22;
        float a = 0.5f * (1.f / (1.f + expf(-adjp[i * 22 + j])) +
                          1.f / (1.f + expf(-adjp[j * 22 + i])));
        c2[e] = (i == j) ? 0.f : a;
    }
    for (int e = tid; e < KTOT; e += 256) aggs[e] = aggw[o * KTOT + e];
    __syncthreads();
    if (tid < 22) {
        float d = 0.f;
        for (int n = 0; n < 22; ++n) d += c2[tid * 22 + n];
        dis[tid] = rsqrtf(d);
    }
    __syncthreads();
    for (int e = tid; e < 484; e += 256) {
        int i = e / 22, j = e - i * 22;
        sm[e] = -dis[i] * c2[e] * dis[j];
    }
    __syncthreads();
    for (int e = tid; e < 484; e += 256) {
        int i = e / 22, j = e - i * 22;
        float acc = 0.f;
        for (int n = 0; n < 22; ++n) acc += sm[i * 22 + n] * sm[n * 22 + j];
        c2[e] = 2.f * acc - (i == j ? 1.f : 0.f);
    }
    __syncthreads();
    // F_q[cp][v] = sum_n aggs[cp*22+n] * Cq[n*22+v]
    for (int e = tid; e < KTOT; e += 256) {
        int cp = e / 22, v = e - cp * 22;
        float a1 = 0.f, a2 = 0.f;
        for (int n = 0; n < 22; ++n) {
            float w = aggs[cp * 22 + n];
            a1 += w * sm[n * 22 + v];
            a2 += w * c2[n * 22 + v];
        }
        F1[e] = a1;
        F2[e] = a2;
    }
    if (kq == 0) {
        float p = 0.f;
        for (int e = tid; e < KTOT; e += 256) p += aggs[e] * chebb[e / 22];
        red[tid] = p;
    }
    __syncthreads();   // covers F1/F2 writes (all blocks) and red (kq==0)
    if (kq == 0) {
#pragma unroll
        for (int st = 128; st > 0; st >>= 1) {
            if (tid < st) red[tid] += red[tid + st];
            __syncthreads();
        }
        if (tid == 0) constv[o] = red[0] + aggb[o];
    }

    // M[o,k] = sum_cp W0[c,cp]*aggs[cp,v] + W1[c,cp]*F1[cp,v] + W2[c,cp]*F2[cp,v]
    const int fo = o >> 4, l15 = o & 15;
    const int kend = (kq + 1) * 352;
    for (int k = kq * 352 + tid; k < kend; k += 256) {
        int c = k / 22, v = k - c * 22;
        const float* w0 = chebw + c * 64;
        float a0 = 0.f, a1 = 0.f, a2 = 0.f;
        for (int cp = 0; cp < 64; ++cp) {
            int idx = cp * 22 + v;
            a0 += w0[cp] * aggs[idx];
            a1 += w0[4096 + cp] * F1[idx];
            a2 += w0[8192 + cp] * F2[idx];
        }
        int ks = k >> 5, r = k & 31, lhi = r >> 3, j = r & 7;
        Mfrag[(((ks * 4 + fo) * 64) + lhi * 16 + l15) * 8 + j] = (__bf16)(a0 + a1 + a2);
    }
}

// ---------------------------------------------------------------------------
// main GEMM: per block (b, t-half of 512): Y[64, th*512:+512] = M @ X_b
// 1024 threads = 16 waves; wave owns t-sub of 32 (two 16-col MFMA tiles).
// x rows read as 2x1KB back-to-back (2 KB DRAM granularity).
// Single 64 KB LDS buffer, reg-staged (global->reg->ds_write) with the
// write-side chunk^kg swizzle (read uses the same involution -> 2-way free).
// Counted vmcnt(4): A-prefetch loads stay in flight across barriers.
// ---------------------------------------------------------------------------
#define WAITV(N) asm volatile("s_waitcnt vmcnt(" #N ")" ::: "memory")
#define BARR do { __builtin_amdgcn_s_barrier(); __builtin_amdgcn_sched_barrier(0); } while (0)
#define SYNCLDS do { asm volatile("s_waitcnt lgkmcnt(0)" ::: "memory"); \
                     __builtin_amdgcn_s_barrier(); __builtin_amdgcn_sched_barrier(0); } while (0)

__global__ __launch_bounds__(1024, 4) void gemm_main(
    const float* __restrict__ x,
    const __bf16* __restrict__ Mfrag,
    const float* __restrict__ constv,
    float* __restrict__ y)
{
    __shared__ float lds[32 * 512];   // 64 KB, single buffer

    // XCD swizzle: 128 blocks -> 16 per XCD (bijective, 128 % 8 == 0)
    const int bid  = ((blockIdx.x & 7) << 4) | (blockIdx.x >> 3);
    const int b    = bid >> 1;
    const int th   = bid & 1;
    const int wave = threadIdx.x >> 6;   // 0..15
    const int lane = threadIdx.x & 63;
    const int tcol = lane & 15;
    const int kg   = lane >> 4;

    const size_t xbase = (size_t)b * ((size_t)KTOT * T_) + (size_t)th * 512;

    // read addressing: lane (kg,tcol), j: needs x[k=kg*8+j][t=wave*32+m*16+tcol]
    // global t-chunk G = wave*2+m stored at LDS chunk G ^ kg (s(row k)=kg)
    const int rd0 = (kg * 8) * 512 + ((((wave << 1) | 0) ^ kg) << 4) + tcol;
    const int rd1 = (kg * 8) * 512 + ((((wave << 1) | 1) ^ kg) << 4) + tcol;

    const __bf16* mf = Mfrag + (size_t)lane * 8;

    f32x4 acc[2][4];
#pragma unroll
    for (int m = 0; m < 2; ++m)
#pragma unroll
        for (int fo = 0; fo < 4; ++fo) acc[m][fo] = (f32x4){0.f, 0.f, 0.f, 0.f};

    f32x4 g[4];
    bf16x8 ac[4], an[4];

    // GLOAD: wave stages rows 2w, 2w+1; instr h: row 2w+(h>>1), half (h&1);
    // each instr = 64 lanes x 16 B contiguous 1 KB.
    auto GLOAD = [&](int ks) {
#pragma unroll
        for (int h = 0; h < 4; ++h) {
            const int r = 2 * wave + (h >> 1);
            const float* src = x + xbase + (size_t)(ks * 32 + r) * T_
                             + (h & 1) * 256 + lane * 4;
            g[h] = *reinterpret_cast<const f32x4*>(src);
        }
    };
    // DSWRITE: row r, source chunk cl = (h&1)*16 + (lane>>2) stored at cl ^ s(r)
    auto DSWRITE = [&]() {
#pragma unroll
        for (int h = 0; h < 4; ++h) {
            const int r  = 2 * wave + (h >> 1);
            const int s  = (r >> 3) & 3;
            const int cl = (h & 1) * 16 + (lane >> 2);
            *reinterpret_cast<f32x4*>(&lds[r * 512 + ((cl ^ s) << 4) + (lane & 3) * 4]) = g[h];
        }
    };
    auto PREFA = [&](bf16x8* dst, int ks) {
        const __bf16* p = mf + (size_t)ks * 2048;
#pragma unroll
        for (int fo = 0; fo < 4; ++fo)
            dst[fo] = *reinterpret_cast<const bf16x8*>(p + fo * 512);
    };
    auto COMPUTE = [&](const bf16x8* a) {
#pragma unroll
        for (int m = 0; m < 2; ++m) {
            const int rb = m ? rd1 : rd0;
            float v[8];
#pragma unroll
            for (int j = 0; j < 8; ++j) v[j] = lds[rb + j * 512];
            bf16x8 bx;
#pragma unroll
            for (int j = 0; j < 8; ++j) bx[j] = (__bf16)v[j];
#pragma unroll
            for (int fo = 0; fo < 4; ++fo)
                acc[m][fo] = __builtin_amdgcn_mfma_f32_16x16x32_bf16(a[fo], bx, acc[m][fo], 0, 0, 0);
        }
    };

    // ---- prologue: tile 0 ----
    GLOAD(0); PREFA(ac, 0);
    WAITV(4);                 // drain G(0), keep A(0) in flight
    DSWRITE(); SYNCLDS;

    // ---- main loop: iters 0..41 ----
    // iter t: GLOAD(t+1); PREFA(t+1); COMPUTE(t); WAITV(4) [drains G(t+1),
    // keeps A(t+1)]; barrier (reads done); DSWRITE; lgkm+barrier.
    for (int t = 0; t < 42; t += 2) {
        GLOAD(t + 1); PREFA(an, t + 1); COMPUTE(ac);
        WAITV(4); BARR; DSWRITE(); SYNCLDS;
        GLOAD(t + 2); PREFA(ac, t + 2); COMPUTE(an);
        WAITV(4); BARR; DSWRITE(); SYNCLDS;
    }
    // ---- iter 42 ----
    GLOAD(43); PREFA(an, 43); COMPUTE(ac);
    WAITV(4); BARR; DSWRITE(); SYNCLDS;
    // ---- iter 43 ----
    COMPUTE(an);

    // ---- store: o = fo*16 + kg*4 + rr, t = th*512 + wave*32 + m*16 + tcol
    float* yp = y + (size_t)b * (O_ * T_) + th * 512 + wave * 32 + tcol;
#pragma unroll
    for (int m = 0; m < 2; ++m)
#pragma unroll
        for (int fo = 0; fo < 4; ++fo)
#pragma unroll
            for (int rr = 0; rr < 4; ++rr) {
                int o = fo * 16 + kg * 4 + rr;
                yp[(size_t)o * T_ + m * 16] = acc[m][fo][rr] + constv[o];
            }
}

// ---------------------------------------------------------------------------
extern "C" void kernel_launch(void* const* d_in, const int* in_sizes, int n_in,
                              void* d_out, int out_size, void* d_ws, size_t ws_size,
                              hipStream_t stream)
{
    (void)in_sizes; (void)n_in; (void)out_size; (void)ws_size;
    const float* x     = (const float*)d_in[0];
    const float* adjp  = (const float*)d_in[1];
    const float* chebw = (const float*)d_in[2];
    const float* chebb = (const float*)d_in[3];
    const float* aggw  = (const float*)d_in[4];
    const float* aggb  = (const float*)d_in[5];
    float* y = (float*)d_out;

    char* ws = (char*)d_ws;
    float*  constv = (float*)(ws);                 // 64 floats
    __bf16* Mfrag  = (__bf16*)(ws + 4096);         // 90112 bf16 (180224 B)

    hipLaunchKernelGGL(prep_all, dim3(256), dim3(256), 0, stream,
                       adjp, chebw, chebb, aggw, aggb, Mfrag, constv);
    hipLaunchKernelGGL(gemm_main, dim3(128), dim3(1024), 0, stream,
                       x, Mfrag, constv, y);
}

// Round 6
// 113.973 us; speedup vs baseline: 1.2317x; 1.2317x over previous
//
#include <hip/hip_runtime.h>
#include <hip/hip_bf16.h>

// Problem constants
#define B_    64
#define C_    64
#define N_    22
#define T_    1024
#define O_    64
#define KTOT  1408      // C_*N_
#define KSTEPS 44       // KTOT/32

typedef __bf16 bf16x8 __attribute__((ext_vector_type(8)));
typedef float  f32x4  __attribute__((ext_vector_type(4)));

typedef __attribute__((address_space(1))) float f32_g;
typedef __attribute__((address_space(3))) float f32_l;

// ---------------------------------------------------------------------------
// prep_all: grid 256 = 64 o x 4 kq. Each block redundantly computes the 22x22
// graph operators + F1/F2 (cheap), then folds its k-range [kq*352,+352) of
// Mfrag in A-fragment-major bf16 layout:
//   Mfrag[((ks*4+fo)*64 + l)*8 + j] = M[o = fo*16 + (l&15),
//                                       k = ks*32 + (l>>4)*8 + j]
// ---------------------------------------------------------------------------
__global__ __launch_bounds__(256) void prep_all(
    const float* __restrict__ adjp,
    const float* __restrict__ chebw,   // [3][64][64]
    const float* __restrict__ chebb,   // [64]
    const float* __restrict__ aggw,    // [64][64][22]
    const float* __restrict__ aggb,    // [64]
    __bf16* __restrict__ Mfrag,        // [176*512]
    float* __restrict__ constv)        // [64]
{
    const int o   = blockIdx.x >> 2;
    const int kq  = blockIdx.x & 3;
    const int tid = threadIdx.x;
    __shared__ float sm[484];     // s = -D^-1/2 A D^-1/2   (C1)
    __shared__ float c2[484];     // adj (temp), then C2 = 2 s^2 - I
    __shared__ float dis[22];
    __shared__ float aggs[KTOT];  // aggw[o,:,:]
    __shared__ float F1[KTOT];
    __shared__ float F2[KTOT];
    __shared__ float red[256];

    for (int e = tid; e < 484; e += 256) {
        int i = e / 22, j = e - i * 22;
        float a = 0.5f * (1.f / (1.f + expf(-adjp[i * 22 + j])) +
                          1.f / (1.f + expf(-adjp[j * 22 + i])));
        c2[e] = (i == j) ? 0.f : a;
    }
    for (int e = tid; e < KTOT; e += 256) aggs[e] = aggw[o * KTOT + e];
    __syncthreads();
    if (tid < 22) {
        float d = 0.f;
        for (int n = 0; n < 22; ++n) d += c2[tid * 22 + n];
        dis[tid] = rsqrtf(d);
    }
    __syncthreads();
    for (int e = tid; e < 484; e += 256) {
        int i = e / 22, j = e - i * 22;
        sm[e] = -dis[i] * c2[e] * dis[j];
    }
    __syncthreads();
    for (int e = tid; e < 484; e += 256) {
        int i = e / 22, j = e - i * 22;
        float acc = 0.f;
        for (int n = 0; n < 22; ++n) acc += sm[i * 22 + n] * sm[n * 22 + j];
        c2[e] = 2.f * acc - (i == j ? 1.f : 0.f);
    }
    __syncthreads();
    // F_q[cp][v] = sum_n aggs[cp*22+n] * Cq[n*22+v]
    for (int e = tid; e < KTOT; e += 256) {
        int cp = e / 22, v = e - cp * 22;
        float a1 = 0.f, a2 = 0.f;
        for (int n = 0; n < 22; ++n) {
            float w = aggs[cp * 22 + n];
            a1 += w * sm[n * 22 + v];
            a2 += w * c2[n * 22 + v];
        }
        F1[e] = a1;
        F2[e] = a2;
    }
    if (kq == 0) {
        float p = 0.f;
        for (int e = tid; e < KTOT; e += 256) p += aggs[e] * chebb[e / 22];
        red[tid] = p;
    }
    __syncthreads();   // covers F1/F2 writes (all blocks) and red (kq==0)
    if (kq == 0) {
#pragma unroll
        for (int st = 128; st > 0; st >>= 1) {
            if (tid < st) red[tid] += red[tid + st];
            __syncthreads();
        }
        if (tid == 0) constv[o] = red[0] + aggb[o];
    }

    // M[o,k] = sum_cp W0[c,cp]*aggs[cp,v] + W1[c,cp]*F1[cp,v] + W2[c,cp]*F2[cp,v]
    const int fo = o >> 4, l15 = o & 15;
    const int kend = (kq + 1) * 352;
    for (int k = kq * 352 + tid; k < kend; k += 256) {
        int c = k / 22, v = k - c * 22;
        const float* w0 = chebw + c * 64;
        float a0 = 0.f, a1 = 0.f, a2 = 0.f;
        for (int cp = 0; cp < 64; ++cp) {
            int idx = cp * 22 + v;
            a0 += w0[cp] * aggs[idx];
            a1 += w0[4096 + cp] * F1[idx];
            a2 += w0[8192 + cp] * F2[idx];
        }
        int ks = k >> 5, r = k & 31, lhi = r >> 3, j = r & 7;
        Mfrag[(((ks * 4 + fo) * 64) + lhi * 16 + l15) * 8 + j] = (__bf16)(a0 + a1 + a2);
    }
}

// ---------------------------------------------------------------------------
// main GEMM: per block (b, t-half of 512): Y[64, th*512:+512] = M @ X_b
// 1024 threads = 16 waves; wave owns t-sub of 32 (two 16-col MFMA tiles).
// global_load_lds direct, 2 x 64 KB LDS buffers of [32 k][512 t] fp32.
// Each row fetched as 2 back-to-back 1 KB instrs -> 2 KB DRAM granularity.
// Stage distance: S(t+2) issued end of iter t, consumed iter t+2 top
// (~2 iters of latency cover). Steady WAITV(4) -- never 0 in main loop.
// Chunk-XOR swizzle on SOURCE (64B units within 256B windows; every 128B
// line still fully covered), same XOR on read -> 2-way bank alias (free).
// ---------------------------------------------------------------------------
#define WAITV(N) asm volatile("s_waitcnt vmcnt(" #N ")" ::: "memory")
#define BARR do { __builtin_amdgcn_s_barrier(); __builtin_amdgcn_sched_barrier(0); } while (0)

__global__ __launch_bounds__(1024, 4) void gemm_main(
    const float* __restrict__ x,
    const __bf16* __restrict__ Mfrag,
    const float* __restrict__ constv,
    float* __restrict__ y)
{
    __shared__ float lds[2 * 16384];   // 2 x [32][512] fp32 = 128 KB

    // XCD swizzle: 128 blocks -> 16 per XCD (bijective, 128 % 8 == 0)
    const int bid  = ((blockIdx.x & 7) << 4) | (blockIdx.x >> 3);
    const int b    = bid >> 1;
    const int th   = bid & 1;
    const int wave = threadIdx.x >> 6;   // 0..15
    const int lane = threadIdx.x & 63;
    const int tcol = lane & 15;
    const int kg   = lane >> 4;
    const int cq   = lane >> 2;          // 64B chunk handled by this lane
    const int ce   = lane & 3;           // 16B sub-chunk

    const size_t xbase = (size_t)b * ((size_t)KTOT * T_) + (size_t)th * 512;

    // read addressing: lane (kg,tcol) j: needs x[k=kg*8+j][t=wave*32+m*16+tcol]
    // global t-chunk G = wave*2+m stored at LDS chunk G ^ kg   (s(row k)=kg)
    const int rd0 = (kg * 8) * 512 + ((((wave << 1) | 0) ^ kg) << 4) + tcol;
    const int rd1 = (kg * 8) * 512 + ((((wave << 1) | 1) ^ kg) << 4) + tcol;

    const __bf16* mf = Mfrag + (size_t)lane * 8;

    f32x4 acc[2][4];
#pragma unroll
    for (int m = 0; m < 2; ++m)
#pragma unroll
        for (int fo = 0; fo < 4; ++fo) acc[m][fo] = (f32x4){0.f, 0.f, 0.f, 0.f};

    // STAGE: wave covers rows 2w, 2w+1; instr h: row 2w+(h>>1), KB-half h&1.
    // LDS dest wave-uniform (linear); source carries the chunk^s permutation.
    auto STAGE = [&](int ks, float* buf) {
#pragma unroll
        for (int h = 0; h < 4; ++h) {
            const int r  = 2 * wave + (h >> 1);
            const int s  = (r >> 3) & 3;
            const int cL = (h & 1) * 16 + cq;        // LDS chunk this lane fills
            const int g  = cL ^ s;                   // global chunk to fetch
            const float* src = x + xbase + (size_t)(ks * 32 + r) * T_ + g * 16 + ce * 4;
            float* dst = buf + r * 512 + (h & 1) * 256;   // wave-uniform base
            __builtin_amdgcn_global_load_lds((const f32_g*)src, (f32_l*)dst, 16, 0, 0);
        }
    };
    auto PREFA = [&](bf16x8* dst, int ks) {
        const __bf16* p = mf + (size_t)ks * 2048;
#pragma unroll
        for (int fo = 0; fo < 4; ++fo)
            dst[fo] = *reinterpret_cast<const bf16x8*>(p + fo * 512);
    };
    auto COMPUTE = [&](const bf16x8* a, const float* buf) {
#pragma unroll
        for (int m = 0; m < 2; ++m) {
            const int rb = m ? rd1 : rd0;
            float v[8];
#pragma unroll
            for (int j = 0; j < 8; ++j) v[j] = buf[rb + j * 512];
            bf16x8 bx;
#pragma unroll
            for (int j = 0; j < 8; ++j) bx[j] = (__bf16)v[j];
#pragma unroll
            for (int fo = 0; fo < 4; ++fo)
                acc[m][fo] = __builtin_amdgcn_mfma_f32_16x16x32_bf16(a[fo], bx, acc[m][fo], 0, 0, 0);
        }
    };

    float* const b0 = lds;
    float* const b1 = lds + 16384;
    bf16x8 ac[4], an[4];

    // ---- prologue: chronological VMEM order [S(0), A(0), S(1)] ----
    STAGE(0, b0);
    PREFA(ac, 0);
    STAGE(1, b1);

    // ---- main loop: iters 0..41 (pairs; even->b0, odd->b1) ----
    // iter t: WAITV(4) [drains A(t),S(t); keeps S(t+1)]; barrier;
    //         PREFA(t+1); COMPUTE(t); barrier (reads done); STAGE(t+2).
    for (int t = 0; t < 42; t += 2) {
        WAITV(4); BARR; PREFA(an, t + 1); COMPUTE(ac, b0); BARR; STAGE(t + 2, b0);
        WAITV(4); BARR; PREFA(ac, t + 2); COMPUTE(an, b1); BARR; STAGE(t + 3, b1);
    }
    // ---- iter 42 ----
    WAITV(4); BARR; PREFA(an, 43); COMPUTE(ac, b0); BARR;
    // ---- iter 43 ----
    WAITV(0); BARR; COMPUTE(an, b1);

    // ---- store: o = fo*16 + kg*4 + rr, t = th*512 + wave*32 + m*16 + tcol
    float* yp = y + (size_t)b * (O_ * T_) + th * 512 + wave * 32 + tcol;
#pragma unroll
    for (int m = 0; m < 2; ++m)
#pragma unroll
        for (int fo = 0; fo < 4; ++fo)
#pragma unroll
            for (int rr = 0; rr < 4; ++rr) {
                int o = fo * 16 + kg * 4 + rr;
                yp[(size_t)o * T_ + m * 16] = acc[m][fo][rr] + constv[o];
            }
}

// ---------------------------------------------------------------------------
extern "C" void kernel_launch(void* const* d_in, const int* in_sizes, int n_in,
                              void* d_out, int out_size, void* d_ws, size_t ws_size,
                              hipStream_t stream)
{
    (void)in_sizes; (void)n_in; (void)out_size; (void)ws_size;
    const float* x     = (const float*)d_in[0];
    const float* adjp  = (const float*)d_in[1];
    const float* chebw = (const float*)d_in[2];
    const float* chebb = (const float*)d_in[3];
    const float* aggw  = (const float*)d_in[4];
    const float* aggb  = (const float*)d_in[5];
    float* y = (float*)d_out;

    char* ws = (char*)d_ws;
    float*  constv = (float*)(ws);                 // 64 floats
    __bf16* Mfrag  = (__bf16*)(ws + 4096);         // 90112 bf16 (180224 B)

    hipLaunchKernelGGL(prep_all, dim3(256), dim3(256), 0, stream,
                       adjp, chebw, chebb, aggw, aggb, Mfrag, constv);
    hipLaunchKernelGGL(gemm_main, dim3(128), dim3(1024), 0, stream,
                       x, Mfrag, constv, y);
}

// Round 7
// 105.048 us; speedup vs baseline: 1.3363x; 1.0850x over previous
//
#include <hip/hip_runtime.h>
#include <hip/hip_bf16.h>

// Problem constants
#define B_    64
#define C_    64
#define N_    22
#define T_    1024
#define O_    64
#define KTOT  1408      // C_*N_
#define KSTEPS 44       // KTOT/32

typedef __bf16 bf16x8 __attribute__((ext_vector_type(8)));
typedef float  f32x4  __attribute__((ext_vector_type(4)));

typedef __attribute__((address_space(1))) float f32_g;
typedef __attribute__((address_space(3))) float f32_l;

// ---------------------------------------------------------------------------
// prep_all: grid 256 = 64 o x 4 kq (unchanged from R5/R6 - validated).
// ---------------------------------------------------------------------------
__global__ __launch_bounds__(256) void prep_all(
    const float* __restrict__ adjp,
    const float* __restrict__ chebw,   // [3][64][64]
    const float* __restrict__ chebb,   // [64]
    const float* __restrict__ aggw,    // [64][64][22]
    const float* __restrict__ aggb,    // [64]
    __bf16* __restrict__ Mfrag,        // [176*512]
    float* __restrict__ constv)        // [64]
{
    const int o   = blockIdx.x >> 2;
    const int kq  = blockIdx.x & 3;
    const int tid = threadIdx.x;
    __shared__ float sm[484];
    __shared__ float c2[484];
    __shared__ float dis[22];
    __shared__ float aggs[KTOT];
    __shared__ float F1[KTOT];
    __shared__ float F2[KTOT];
    __shared__ float red[256];

    for (int e = tid; e < 484; e += 256) {
        int i = e / 22, j = e - i * 22;
        float a = 0.5f * (1.f / (1.f + expf(-adjp[i * 22 + j])) +
                          1.f / (1.f + expf(-adjp[j * 22 + i])));
        c2[e] = (i == j) ? 0.f : a;
    }
    for (int e = tid; e < KTOT; e += 256) aggs[e] = aggw[o * KTOT + e];
    __syncthreads();
    if (tid < 22) {
        float d = 0.f;
        for (int n = 0; n < 22; ++n) d += c2[tid * 22 + n];
        dis[tid] = rsqrtf(d);
    }
    __syncthreads();
    for (int e = tid; e < 484; e += 256) {
        int i = e / 22, j = e - i * 22;
        sm[e] = -dis[i] * c2[e] * dis[j];
    }
    __syncthreads();
    for (int e = tid; e < 484; e += 256) {
        int i = e / 22, j = e - i * 22;
        float acc = 0.f;
        for (int n = 0; n < 22; ++n) acc += sm[i * 22 + n] * sm[n * 22 + j];
        c2[e] = 2.f * acc - (i == j ? 1.f : 0.f);
    }
    __syncthreads();
    for (int e = tid; e < KTOT; e += 256) {
        int cp = e / 22, v = e - cp * 22;
        float a1 = 0.f, a2 = 0.f;
        for (int n = 0; n < 22; ++n) {
            float w = aggs[cp * 22 + n];
            a1 += w * sm[n * 22 + v];
            a2 += w * c2[n * 22 + v];
        }
        F1[e] = a1;
        F2[e] = a2;
    }
    if (kq == 0) {
        float p = 0.f;
        for (int e = tid; e < KTOT; e += 256) p += aggs[e] * chebb[e / 22];
        red[tid] = p;
    }
    __syncthreads();
    if (kq == 0) {
#pragma unroll
        for (int st = 128; st > 0; st >>= 1) {
            if (tid < st) red[tid] += red[tid + st];
            __syncthreads();
        }
        if (tid == 0) constv[o] = red[0] + aggb[o];
    }

    const int fo = o >> 4, l15 = o & 15;
    const int kend = (kq + 1) * 352;
    for (int k = kq * 352 + tid; k < kend; k += 256) {
        int c = k / 22, v = k - c * 22;
        const float* w0 = chebw + c * 64;
        float a0 = 0.f, a1 = 0.f, a2 = 0.f;
        for (int cp = 0; cp < 64; ++cp) {
            int idx = cp * 22 + v;
            a0 += w0[cp] * aggs[idx];
            a1 += w0[4096 + cp] * F1[idx];
            a2 += w0[8192 + cp] * F2[idx];
        }
        int ks = k >> 5, r = k & 31, lhi = r >> 3, j = r & 7;
        Mfrag[(((ks * 4 + fo) * 64) + lhi * 16 + l15) * 8 + j] = (__bf16)(a0 + a1 + a2);
    }
}

// ---------------------------------------------------------------------------
// main GEMM: R4 structure (256 blocks = 64b x 4tq, t-tile 256, 3x32KB LDS,
// stage distance 2, counted vmcnt) but 1024 threads = 16 waves (4/SIMD):
// doubles per-CU outstanding-load depth. Wave owns one 16-col strip.
// Swizzle: LDS chunk c (16 floats) of row r holds global chunk c ^ (r>>3);
// read chunk = wave ^ kg -> 2-way bank alias (free).
// ---------------------------------------------------------------------------
#define WAITV(N) asm volatile("s_waitcnt vmcnt(" #N ")" ::: "memory")
#define BARR do { __builtin_amdgcn_s_barrier(); __builtin_amdgcn_sched_barrier(0); } while (0)

__global__ __launch_bounds__(1024, 4) void gemm_main(
    const float* __restrict__ x,
    const __bf16* __restrict__ Mfrag,
    const float* __restrict__ constv,
    float* __restrict__ y)
{
    __shared__ float lds[3 * 8192];   // 3 x [32 k][256 t] fp32 = 96 KB

    // XCD swizzle: 256 blocks -> 32 per XCD (bijective, 256 % 8 == 0);
    // same-b blocks (4 consecutive logical ids) colocate on one XCD.
    const int bid  = ((blockIdx.x & 7) << 5) | (blockIdx.x >> 3);
    const int b    = bid >> 2;
    const int tq   = bid & 3;
    const int wave = threadIdx.x >> 6;   // 0..15
    const int lane = threadIdx.x & 63;
    const int tcol = lane & 15;
    const int kg   = lane >> 4;

    const size_t xbase = (size_t)b * ((size_t)KTOT * T_) + (size_t)tq * 256;

    // read: lane (kg,tcol), j: needs x[k=kg*8+j][t=wave*16+tcol]
    // global chunk `wave` of row k stored at LDS chunk wave ^ (k>>3) = wave^kg
    const int rd = (kg * 8) * 256 + ((wave ^ kg) << 4) + tcol;

    const __bf16* mf = Mfrag + (size_t)lane * 8;

    f32x4 acc[4];
#pragma unroll
    for (int fo = 0; fo < 4; ++fo) acc[fo] = (f32x4){0.f, 0.f, 0.f, 0.f};

    // STAGE: wave stages rows 2w, 2w+1 (1 KB each, one gload_lds per row).
    // LDS dest wave-uniform + lane*16B (linear); source pre-swizzled.
    auto STAGE = [&](int ks, float* buf) {
#pragma unroll
        for (int h = 0; h < 2; ++h) {
            const int r  = 2 * wave + h;
            const int s  = r >> 3;                   // 0..3
            const int g  = (lane >> 2) ^ s;          // global chunk for LDS chunk lane>>2
            const float* src = x + xbase + (size_t)(ks * 32 + r) * T_
                             + g * 16 + (lane & 3) * 4;
            float* dst = buf + r * 256;              // wave-uniform base
            __builtin_amdgcn_global_load_lds((const f32_g*)src, (f32_l*)dst, 16, 0, 0);
        }
    };
    auto PREFA = [&](bf16x8* dst, int ks) {
        const __bf16* p = mf + (size_t)ks * 2048;
#pragma unroll
        for (int fo = 0; fo < 4; ++fo)
            dst[fo] = *reinterpret_cast<const bf16x8*>(p + fo * 512);
    };
    auto COMPUTE = [&](const bf16x8* a, const float* buf) {
        float v[8];
#pragma unroll
        for (int j = 0; j < 8; ++j) v[j] = buf[rd + j * 256];
        bf16x8 bx;
#pragma unroll
        for (int j = 0; j < 8; ++j) bx[j] = (__bf16)v[j];
#pragma unroll
        for (int fo = 0; fo < 4; ++fo)
            acc[fo] = __builtin_amdgcn_mfma_f32_16x16x32_bf16(a[fo], bx, acc[fo], 0, 0, 0);
    };

    float* const b0 = lds;
    float* const b1 = lds + 8192;
    float* const b2 = lds + 16384;
    bf16x8 ac[4], an[4];

    // ---- prologue: chronological VMEM order [S0(2), A0(4), S1(2)] ----
    STAGE(0, b0);
    PREFA(ac, 0);
    STAGE(1, b1);

    // ---- main loop: tiles 0..41 ----
    // tile j: WAITV(2) drains {S(j),A(j)}, keeps S(j+1); barrier;
    //         PREFA(j+1); STAGE(j+2 -> buf[(j+2)%3]); COMPUTE(j).
    for (int i = 0; i < 42; i += 6) {
        WAITV(2); BARR; PREFA(an, i + 1); STAGE(i + 2, b2); COMPUTE(ac, b0);
        WAITV(2); BARR; PREFA(ac, i + 2); STAGE(i + 3, b0); COMPUTE(an, b1);
        WAITV(2); BARR; PREFA(an, i + 3); STAGE(i + 4, b1); COMPUTE(ac, b2);
        WAITV(2); BARR; PREFA(ac, i + 4); STAGE(i + 5, b2); COMPUTE(an, b0);
        WAITV(2); BARR; PREFA(an, i + 5); STAGE(i + 6, b0); COMPUTE(ac, b1);
        WAITV(2); BARR; PREFA(ac, i + 6); STAGE(i + 7, b1); COMPUTE(an, b2);
    }

    // ---- tail: tiles 42 (b0, ac), 43 (b1, an) ----
    WAITV(2); BARR; PREFA(an, 43); COMPUTE(ac, b0);
    WAITV(0); BARR; COMPUTE(an, b1);

    // ---- store: o = fo*16 + kg*4 + rr, t = tq*256 + wave*16 + tcol ----
    float* yp = y + (size_t)b * (O_ * T_) + tq * 256 + wave * 16 + tcol;
#pragma unroll
    for (int fo = 0; fo < 4; ++fo)
#pragma unroll
        for (int rr = 0; rr < 4; ++rr) {
            int o = fo * 16 + kg * 4 + rr;
            yp[(size_t)o * T_] = acc[fo][rr] + constv[o];
        }
}

// ---------------------------------------------------------------------------
extern "C" void kernel_launch(void* const* d_in, const int* in_sizes, int n_in,
                              void* d_out, int out_size, void* d_ws, size_t ws_size,
                              hipStream_t stream)
{
    (void)in_sizes; (void)n_in; (void)out_size; (void)ws_size;
    const float* x     = (const float*)d_in[0];
    const float* adjp  = (const float*)d_in[1];
    const float* chebw = (const float*)d_in[2];
    const float* chebb = (const float*)d_in[3];
    const float* aggw  = (const float*)d_in[4];
    const float* aggb  = (const float*)d_in[5];
    float* y = (float*)d_out;

    char* ws = (char*)d_ws;
    float*  constv = (float*)(ws);                 // 64 floats
    __bf16* Mfrag  = (__bf16*)(ws + 4096);         // 90112 bf16 (180224 B)

    hipLaunchKernelGGL(prep_all, dim3(256), dim3(256), 0, stream,
                       adjp, chebw, chebb, aggw, aggb, Mfrag, constv);
    hipLaunchKernelGGL(gemm_main, dim3(256), dim3(1024), 0, stream,
                       x, Mfrag, constv, y);
}